// Round 3
// baseline (1129.406 us; speedup 1.0000x reference)
//
#include <hip/hip_runtime.h>
#include <math.h>

#define D 128
#define TILE 64
#define PADX 132   // xs row stride (floats)
#define PADW 68    // w half row stride (floats)

// ---------------- zero the stats block (512 floats) ----------------
__global__ void zero_stats_k(float* stats) {
    stats[blockIdx.x * blockDim.x + threadIdx.x] = 0.0f;
}

// ---------------- K1: fused node linear (U,V,B,C) ----------------
__global__ __launch_bounds__(256, 2)
void node_linear_k(const float* __restrict__ h_in,
                   const float* __restrict__ Uw, const float* __restrict__ Ub,
                   const float* __restrict__ Vw, const float* __restrict__ Vb,
                   const float* __restrict__ Bw, const float* __restrict__ Bb,
                   const float* __restrict__ Cw, const float* __restrict__ Cb,
                   float* __restrict__ outU, float* __restrict__ outV,
                   float* __restrict__ outB, float* __restrict__ outC,
                   int M)
{
    __shared__ float xs[TILE * PADX];
    __shared__ float wsm[D * PADW];
    const int tid = threadIdx.x;
    const int row0 = blockIdx.x * TILE;

    // stage x tile (64 x 128) as float4
    for (int f = tid; f < TILE * D / 4; f += 256) {
        int r = f >> 5, c4 = f & 31;
        int row = row0 + r;
        float4 v = make_float4(0.f, 0.f, 0.f, 0.f);
        if (row < M) v = *reinterpret_cast<const float4*>(h_in + (size_t)row * D + c4 * 4);
        *reinterpret_cast<float4*>(&xs[r * PADX + c4 * 4]) = v;
    }

    const int tx = tid & 31;   // col group: cols {tx, tx+32, tx+64, tx+96}
    const int ty = tid >> 5;   // row group: rows ty*8 .. ty*8+7

    const float* Ws[4] = {Uw, Vw, Bw, Cw};
    const float* Bs[4] = {Ub, Vb, Bb, Cb};
    float*       Os[4] = {outU, outV, outB, outC};

    #pragma unroll
    for (int wsel = 0; wsel < 4; ++wsel) {
        float acc[8][4];
        #pragma unroll
        for (int r = 0; r < 8; ++r)
            #pragma unroll
            for (int j = 0; j < 4; ++j) acc[r][j] = 0.f;

        const float* W = Ws[wsel];
        #pragma unroll
        for (int half = 0; half < 2; ++half) {
            __syncthreads();  // protect wsm (and xs on first pass)
            for (int f = tid; f < D * 64 / 4; f += 256) {
                int j = f >> 4, k4 = f & 15;
                float4 v = *reinterpret_cast<const float4*>(W + (size_t)j * D + half * 64 + k4 * 4);
                *reinterpret_cast<float4*>(&wsm[j * PADW + k4 * 4]) = v;
            }
            __syncthreads();
            #pragma unroll 4
            for (int k4 = 0; k4 < 16; ++k4) {
                float4 wv[4];
                #pragma unroll
                for (int jj = 0; jj < 4; ++jj)
                    wv[jj] = *reinterpret_cast<const float4*>(&wsm[(tx + 32 * jj) * PADW + k4 * 4]);
                #pragma unroll
                for (int r = 0; r < 8; ++r) {
                    float4 av = *reinterpret_cast<const float4*>(&xs[(ty * 8 + r) * PADX + half * 64 + k4 * 4]);
                    #pragma unroll
                    for (int jj = 0; jj < 4; ++jj)
                        acc[r][jj] += av.x * wv[jj].x + av.y * wv[jj].y + av.z * wv[jj].z + av.w * wv[jj].w;
                }
            }
        }
        const float* bias = Bs[wsel];
        float* O = Os[wsel];
        float bv[4];
        #pragma unroll
        for (int jj = 0; jj < 4; ++jj) bv[jj] = bias[tx + 32 * jj];
        #pragma unroll
        for (int r = 0; r < 8; ++r) {
            int row = row0 + ty * 8 + r;
            if (row < M) {
                #pragma unroll
                for (int jj = 0; jj < 4; ++jj)
                    O[(size_t)row * D + tx + 32 * jj] = acc[r][jj] + bv[jj];
            }
        }
    }
}

// ---------------- K2: fused edge kernel ----------------
// Ae GEMM + gather Bh/Ch -> out_e (pre-BN), inline e-stats,
// msgs = sigmoid(e_in)*Vh[src] atomically accumulated into out_h (holds Uh).
__global__ __launch_bounds__(256, 2)
void edge_k(const float* __restrict__ e_in,
            const int* __restrict__ eidx,   // [2][E] int32: dst row then src row
            const float* __restrict__ Aw, const float* __restrict__ Ab,
            const float* __restrict__ Vh, const float* __restrict__ Bh,
            const float* __restrict__ Ch,
            float* __restrict__ out_h, float* __restrict__ out_e,
            float* __restrict__ e_sum, float* __restrict__ e_sq,
            int E)
{
    __shared__ float xs[TILE * PADX];
    __shared__ float wsm[D * PADW];
    __shared__ float sred[1024];
    __shared__ float qred[1024];
    const int tid = threadIdx.x;
    const int e0 = blockIdx.x * TILE;

    for (int f = tid; f < TILE * D / 4; f += 256) {
        int r = f >> 5, c4 = f & 31;
        float4 v = make_float4(0.f, 0.f, 0.f, 0.f);
        if (e0 + r < E) v = *reinterpret_cast<const float4*>(e_in + (size_t)(e0 + r) * D + c4 * 4);
        *reinterpret_cast<float4*>(&xs[r * PADX + c4 * 4]) = v;
    }

    const int tx = tid & 31, ty = tid >> 5;
    float acc[8][4];
    #pragma unroll
    for (int r = 0; r < 8; ++r)
        #pragma unroll
        for (int j = 0; j < 4; ++j) acc[r][j] = 0.f;

    #pragma unroll
    for (int half = 0; half < 2; ++half) {
        __syncthreads();
        for (int f = tid; f < D * 64 / 4; f += 256) {
            int j = f >> 4, k4 = f & 15;
            float4 v = *reinterpret_cast<const float4*>(Aw + (size_t)j * D + half * 64 + k4 * 4);
            *reinterpret_cast<float4*>(&wsm[j * PADW + k4 * 4]) = v;
        }
        __syncthreads();
        #pragma unroll 4
        for (int k4 = 0; k4 < 16; ++k4) {
            float4 wv[4];
            #pragma unroll
            for (int jj = 0; jj < 4; ++jj)
                wv[jj] = *reinterpret_cast<const float4*>(&wsm[(tx + 32 * jj) * PADW + k4 * 4]);
            #pragma unroll
            for (int r = 0; r < 8; ++r) {
                float4 av = *reinterpret_cast<const float4*>(&xs[(ty * 8 + r) * PADX + half * 64 + k4 * 4]);
                #pragma unroll
                for (int jj = 0; jj < 4; ++jj)
                    acc[r][jj] += av.x * wv[jj].x + av.y * wv[jj].y + av.z * wv[jj].z + av.w * wv[jj].w;
            }
        }
    }

    float bv[4];
    #pragma unroll
    for (int jj = 0; jj < 4; ++jj) bv[jj] = Ab[tx + 32 * jj];

    float s[4] = {0.f, 0.f, 0.f, 0.f}, q[4] = {0.f, 0.f, 0.f, 0.f};
    #pragma unroll
    for (int r = 0; r < 8; ++r) {
        int e = e0 + ty * 8 + r;
        if (e < E) {
            int dn = eidx[e];
            int sn = eidx[(size_t)E + e];
            #pragma unroll
            for (int jj = 0; jj < 4; ++jj) {
                int col = tx + 32 * jj;
                float pre = acc[r][jj] + bv[jj]
                          + Bh[(size_t)dn * D + col] + Ch[(size_t)sn * D + col];
                out_e[(size_t)e * D + col] = pre;
                s[jj] += pre;
                q[jj] += pre * pre;
                float ein = xs[(ty * 8 + r) * PADX + col];
                float msg = (1.f / (1.f + __expf(-ein))) * Vh[(size_t)sn * D + col];
                unsafeAtomicAdd(&out_h[(size_t)dn * D + col], msg);
            }
        }
    }

    // reduce per-column stats across ty and atomically add once per block
    #pragma unroll
    for (int jj = 0; jj < 4; ++jj) {
        sred[(jj * 32 + tx) * 8 + ty] = s[jj];
        qred[(jj * 32 + tx) * 8 + ty] = q[jj];
    }
    __syncthreads();
    if (tid < 128) {
        float ss = 0.f, qq = 0.f;
        #pragma unroll
        for (int t = 0; t < 8; ++t) { ss += sred[tid * 8 + t]; qq += qred[tid * 8 + t]; }
        int jj = tid >> 5, txx = tid & 31;
        int col = txx + 32 * jj;
        unsafeAtomicAdd(&e_sum[col], ss);
        unsafeAtomicAdd(&e_sq[col], qq);
    }
}

// ---------------- K3: column stats over a [rows x 128] matrix ----------------
__global__ void col_stats_k(const float* __restrict__ X, int rows,
                            float* __restrict__ sum, float* __restrict__ sumsq)
{
    __shared__ float sr[2][128], qr[2][128];
    int col = threadIdx.x & 127;
    int rp = threadIdx.x >> 7;
    float s = 0.f, q = 0.f;
    for (int r = blockIdx.x * 2 + rp; r < rows; r += gridDim.x * 2) {
        float v = X[(size_t)r * D + col];
        s += v; q += v * v;
    }
    sr[rp][col] = s; qr[rp][col] = q;
    __syncthreads();
    if (threadIdx.x < 128) {
        unsafeAtomicAdd(&sum[col],   sr[0][col] + sr[1][col]);
        unsafeAtomicAdd(&sumsq[col], qr[0][col] + qr[1][col]);
    }
}

// ---------------- K4/K5: in-place BN + ReLU + residual ----------------
__global__ void finalize_k(const float* __restrict__ res_in,
                           float* __restrict__ out,
                           const float* __restrict__ sum, const float* __restrict__ sumsq,
                           const float* __restrict__ gamma, const float* __restrict__ beta,
                           float cntInv, int rows)
{
    int col = threadIdx.x & 127;
    float mu  = sum[col] * cntInv;
    float var = sumsq[col] * cntInv - mu * mu;
    float inv = rsqrtf(var + 1e-5f);
    float g = gamma[col] * inv;
    float b = beta[col];
    int rp = threadIdx.x >> 7;
    for (int r = blockIdx.x * 2 + rp; r < rows; r += gridDim.x * 2) {
        size_t o = (size_t)r * D + col;
        float x = out[o];
        float bn = g * (x - mu) + b;
        out[o] = res_in[o] + fmaxf(bn, 0.f);
    }
}

extern "C" void kernel_launch(void* const* d_in, const int* in_sizes, int n_in,
                              void* d_out, int out_size, void* d_ws, size_t ws_size,
                              hipStream_t stream)
{
    const float* h_in = (const float*)d_in[0];
    const float* e_in = (const float*)d_in[1];
    const int*   eidx = (const int*)d_in[2];
    const float* Uw = (const float*)d_in[3];  const float* Ub = (const float*)d_in[4];
    const float* Vw = (const float*)d_in[5];  const float* Vb = (const float*)d_in[6];
    const float* Aw = (const float*)d_in[7];  const float* Ab = (const float*)d_in[8];
    const float* Bw = (const float*)d_in[9];  const float* Bb = (const float*)d_in[10];
    const float* Cw = (const float*)d_in[11]; const float* Cb = (const float*)d_in[12];
    const float* hg = (const float*)d_in[13]; const float* hb = (const float*)d_in[14];
    const float* eg = (const float*)d_in[15]; const float* eb = (const float*)d_in[16];

    const int N = in_sizes[0] / D;
    const int E = in_sizes[1] / D;

    float* out_h = (float*)d_out;
    float* out_e = out_h + (size_t)N * D;

    float* ws = (float*)d_ws;
    float* Vh = ws;
    float* Bh = Vh + (size_t)N * D;
    float* Ch = Bh + (size_t)N * D;
    float* stats = Ch + (size_t)N * D;
    float* h_sum = stats;       float* h_sq = stats + 128;
    float* e_sum = stats + 256; float* e_sq = stats + 384;

    zero_stats_k<<<1, 512, 0, stream>>>(stats);
    node_linear_k<<<(N + TILE - 1) / TILE, 256, 0, stream>>>(
        h_in, Uw, Ub, Vw, Vb, Bw, Bb, Cw, Cb, out_h, Vh, Bh, Ch, N);
    edge_k<<<(E + TILE - 1) / TILE, 256, 0, stream>>>(
        e_in, eidx, Aw, Ab, Vh, Bh, Ch, out_h, out_e, e_sum, e_sq, E);
    col_stats_k<<<256, 256, 0, stream>>>(out_h, N, h_sum, h_sq);
    finalize_k<<<256, 256, 0, stream>>>(h_in, out_h, h_sum, h_sq, hg, hb, 1.0f / (float)N, N);
    finalize_k<<<2048, 256, 0, stream>>>(e_in, out_e, e_sum, e_sq, eg, eb, 1.0f / (float)E, E);
}